// Round 11
// baseline (524.775 us; speedup 1.0000x reference)
//
#include <hip/hip_runtime.h>
#include <hip/hip_bf16.h>

#define DI static __device__ __forceinline__

typedef __attribute__((ext_vector_type(8), may_alias)) short short8;
typedef __attribute__((ext_vector_type(4), may_alias)) short short4a;
typedef __attribute__((ext_vector_type(4), may_alias)) float floatx4a;
typedef __attribute__((ext_vector_type(4))) float floatx4;

constexpr int Bsz = 64, Nseq = 512, Cdim = 768, NH = 12, HD = 64;
constexpr int QS = Bsz * NH * Nseq * HD;  // 25165824
// q is pre-scaled by 0.125*log2(e); bias pre-scaled by log2(e); attn uses exp2.
constexpr float QK_PRESCALE = 0.18033688011112042f;  // 0.125 * log2(e)
constexpr float LOG2E = 1.4426950408889634f;

DI ushort f2bf(float f) {
  union { float f; unsigned u; } v; v.f = f;
  unsigned r = v.u + 0x7FFF + ((v.u >> 16) & 1);
  return (ushort)(r >> 16);
}
DI float bf2f(ushort u) {
  union { unsigned u; float f; } v; v.u = ((unsigned)u) << 16;
  return v.f;
}

// async global->LDS, 16B per lane. LDS dest is wave-uniform base + lane*16.
DI void gload_lds16(const ushort* g, ushort* l) {
  __builtin_amdgcn_global_load_lds(
      (const __attribute__((address_space(1))) unsigned int*)g,
      (__attribute__((address_space(3))) unsigned int*)l, 16, 0, 0);
}

// ------------- fp32 -> bf16 converters -------
__global__ void cvt8(const float* __restrict__ s, ushort* __restrict__ d, int n) {
  int i = (blockIdx.x * 256 + threadIdx.x) * 8;
  if (i >= n) return;
  floatx4a a = *(const floatx4a*)(s + i);
  floatx4a b = *(const floatx4a*)(s + i + 4);
  short8 r;
  r[0] = (short)f2bf(a[0]); r[1] = (short)f2bf(a[1]);
  r[2] = (short)f2bf(a[2]); r[3] = (short)f2bf(a[3]);
  r[4] = (short)f2bf(b[0]); r[5] = (short)f2bf(b[1]);
  r[6] = (short)f2bf(b[2]); r[7] = (short)f2bf(b[3]);
  *(short8*)(d + i) = r;
}
// bias table converter: pre-multiplies by log2(e)
__global__ void cvt1s(const float* __restrict__ s, ushort* __restrict__ d, int n) {
  int i = blockIdx.x * 256 + threadIdx.x;
  if (i < n) d[i] = f2bf(s[i] * LOG2E);
}

// ------------- Stage 1: qkv = x @ qkv_w^T -----------------------------------
// THIS round: 256x128 tile + 3-BUFFER rotation (depth-2 prefetch).
// kt's 6 staging loads are issued TWO iterations before consumption ->
// vmcnt(12) has ~2 compute phases + 4 barriers of slack and never blocks
// (the old depth-1 vmcnt(8) was the measured ~3.5x iteration-wall gap).
// Grid 2304 = exactly 9 blocks/CU (balanced; old 1152 = 4.5 + tail).
// LDS 3 x (A 32KB + W 16KB) = 144KB < 160KB. Buffer (kt+2)%3 was last
// read at kt-1, drained by kt-1's lgkmcnt(0)+barrier before we write it.
__global__ __launch_bounds__(512, 2) void qkv_gemm(
    const ushort* __restrict__ x, const ushort* __restrict__ w,
    ushort* __restrict__ qo, ushort* __restrict__ ko, ushort* __restrict__ vo)
{
  __shared__ __align__(16) ushort As[3][256 * 64];   // 96 KB
  __shared__ __align__(16) ushort Ws[3][128 * 64];   // 48 KB (144 KB total)
  // XCD swizzle: 2304 blocks, 8 XCDs -> 288 contiguous per XCD.
  const int id = blockIdx.y * 18 + blockIdx.x;
  const int swz = (id & 7) * 288 + (id >> 3);
  const int bm = swz / 18;     // 0..127  (32768/256)
  const int bn = swz % 18;     // 0..17   (2304/128)
  const int t = threadIdx.x;
  const int wv = t >> 6, ln = t & 63, lq = ln >> 4, lm = ln & 15;
  const int wm = wv >> 1, wn = wv & 1;   // wave tile: rows wm*64+, cols wn*64+

  const int srow = ln >> 3;              // 0..7 within an 8-row chunk (= row&7)
  const int scol = (((ln & 7) ^ srow) << 3);   // T2 pre-swizzled source col
  const int cswz = (lm & 7) << 3;              // read-side XOR

  floatx4 acc[4][4];
  #pragma unroll
  for (int i = 0; i < 4; ++i)
    #pragma unroll
    for (int j = 0; j < 4; ++j) acc[i][j] = (floatx4)0.f;

  // stage one K-tile: 6 gload_lds per thread (4 A-chunks + 2 W-chunks)
  auto stage = [&](int buf, int kt) {
    #pragma unroll
    for (int p = 0; p < 4; ++p) {
      int c = wv * 4 + p;                // A chunk 0..31, 8 rows each
      int row = c * 8 + srow;
      gload_lds16(&x[(size_t)(bm * 256 + row) * Cdim + kt * 64 + scol],
                  &As[buf][c * 512]);
    }
    #pragma unroll
    for (int p = 0; p < 2; ++p) {
      int c = wv * 2 + p;                // W chunk 0..15, 8 rows each
      int row = c * 8 + srow;
      gload_lds16(&w[(size_t)(bn * 128 + row) * Cdim + kt * 64 + scol],
                  &Ws[buf][c * 512]);
    }
  };

  stage(0, 0);
  stage(1, 1);
  for (int kt = 0; kt < 12; ++kt) {
    const int cur = kt % 3;
    if (kt <= 9) {
      stage((cur + 2) % 3, kt + 2);
      asm volatile("s_waitcnt vmcnt(12)" ::: "memory");  // kt's 6 loads done
    } else if (kt == 10) {
      asm volatile("s_waitcnt vmcnt(6)" ::: "memory");
    } else {
      asm volatile("s_waitcnt vmcnt(0)" ::: "memory");
    }
    __builtin_amdgcn_s_barrier();
    #pragma unroll
    for (int ks = 0; ks < 2; ++ks) {
      short8 af[4], bfr[4];
      #pragma unroll
      for (int i = 0; i < 4; ++i)
        af[i] = *(const short8*)&As[cur][(wm * 64 + i * 16 + lm) * 64 +
                                         ((ks * 32 + lq * 8) ^ cswz)];
      #pragma unroll
      for (int j = 0; j < 4; ++j)
        bfr[j] = *(const short8*)&Ws[cur][(wn * 64 + j * 16 + lm) * 64 +
                                          ((ks * 32 + lq * 8) ^ cswz)];
      #pragma unroll
      for (int i = 0; i < 4; ++i)
        #pragma unroll
        for (int j = 0; j < 4; ++j)
          acc[i][j] = __builtin_amdgcn_mfma_f32_16x16x32_bf16(af[i], bfr[j], acc[i][j], 0, 0, 0);
    }
    asm volatile("s_waitcnt lgkmcnt(0)" ::: "memory");  // our reads done
    __builtin_amdgcn_s_barrier();                       // before buf overwrite
  }

  // Epilogue. 64-col wave block lies entirely in one (which, head).
  const int cbase = bn * 128 + wn * 64;
  const int which = cbase / Cdim;            // 0=q 1=k 2=v
  const int h = (cbase % Cdim) >> 6;
  const float osc = (which == 0) ? QK_PRESCALE : 1.f;
  #pragma unroll
  for (int i = 0; i < 4; ++i) {
    int gm0 = bm * 256 + wm * 64 + i * 16 + lq * 4;
    int b = gm0 >> 9, ns0 = gm0 & 511;       // 4-run stays within one (b,ns-run)
    #pragma unroll
    for (int j = 0; j < 4; ++j) {
      int d = j * 16 + lm;
      if (which == 2) {
        short4a v4;
        #pragma unroll
        for (int r = 0; r < 4; ++r) v4[r] = (short)f2bf(acc[i][j][r]);
        *(short4a*)&vo[(size_t)((b * NH + h) * HD + d) * Nseq + ns0] = v4;
      } else {
        ushort* outp = which == 0 ? qo : ko;
        #pragma unroll
        for (int r = 0; r < 4; ++r)
          outp[(size_t)((b * NH + h) * Nseq + ns0 + r) * HD + d] = f2bf(acc[i][j][r] * osc);
      }
    }
  }
}

// ------------- Stage 2: flash attention, 2 q-tiles per block (unchanged) ----
__global__ __launch_bounds__(256) void attn_kernel(
    const ushort* __restrict__ q, const ushort* __restrict__ k,
    const ushort* __restrict__ vt, const ushort* __restrict__ bt,
    ushort* __restrict__ ao)
{
  __shared__ __align__(16) ushort Ks[64 * 72];
  __shared__ __align__(16) ushort Vs[64 * 72];   // Vt tile: [d][n]
  __shared__ __align__(16) ushort Ps[64 * 72];
  __shared__ float biasStrip[640];
  const int blk = blockIdx.x;
  const int xcd = blk & 7;
  const int slot = blk >> 3;               // 0..383
  const int qp = slot & 3;                 // q-tile PAIR {2qp, 2qp+1}
  const int bh = xcd * 96 + (slot >> 2);   // head pinned to one XCD
  const int h = bh % NH, b = bh / NH;
  const int t = threadIdx.x;
  const int wv = t >> 6, ln = t & 63, lq = ln >> 4, lm = ln & 15;
  const size_t base = (size_t)bh * (Nseq * HD);
  const int qt0 = qp * 2;

  // Q fragments for both q-tiles straight from global (per-lane 16B).
  short8 qa[2][2];
  #pragma unroll
  for (int j = 0; j < 2; ++j)
    #pragma unroll
    for (int ks = 0; ks < 2; ++ks)
      qa[j][ks] = *(const short8*)&q[base +
          (size_t)((qt0 + j) * 64 + wv * 16 + lm) * HD + ks * 32 + lq * 8];

  // bias strip: rel = qt0*64 + j, j in [0,639]; max index (6*64+638)=1022 OK.
  for (int j = t; j < 640; j += 256)
    biasStrip[j] = bf2f(bt[(qt0 * 64 + j) * NH + h]);

  floatx4 o[2][4];
  float lrow[2][4];
  #pragma unroll
  for (int j = 0; j < 2; ++j)
    #pragma unroll
    for (int i = 0; i < 4; ++i) { o[j][i] = (floatx4)0.f; lrow[j][i] = 0.f; }

  for (int kt = 0; kt < Nseq / 64; ++kt) {
    #pragma unroll
    for (int i = 0; i < 2; ++i) {
      int id = t + 256 * i;
      int r = id >> 3, c = (id & 7) << 3;
      *(short8*)&Ks[r * 72 + c] =
          *(const short8*)&k[base + (size_t)(kt * 64 + r) * HD + c];
      *(short8*)&Vs[r * 72 + c] =                      // row r = d, col c = n
          *(const short8*)&vt[base + (size_t)r * Nseq + kt * 64 + c];
    }
    __syncthreads();   // staging visible (also covers biasStrip on kt==0)

    #pragma unroll
    for (int j = 0; j < 2; ++j) {        // q-tile within the pair
      floatx4 s[4];
      #pragma unroll
      for (int cb = 0; cb < 4; ++cb) s[cb] = (floatx4)0.f;
      #pragma unroll
      for (int ks = 0; ks < 2; ++ks) {
        #pragma unroll
        for (int cb = 0; cb < 4; ++cb) {
          short8 bfr = *(const short8*)&Ks[(cb * 16 + lm) * 72 + ks * 32 + lq * 8];
          s[cb] = __builtin_amdgcn_mfma_f32_16x16x32_bf16(qa[j][ks], bfr, s[cb], 0, 0, 0);
        }
      }

      // p = exp2(s + bias); bias index = (j-kt)*64 + 511 + (row-col)
      const int bbase = j * 64 - kt * 64 + 511;
      #pragma unroll
      for (int r = 0; r < 4; ++r) {
        int row_in = wv * 16 + lq * 4 + r;
        #pragma unroll
        for (int cb = 0; cb < 4; ++cb) {
          int col_in = cb * 16 + lm;
          float p = __builtin_amdgcn_exp2f(s[cb][r] +
                                           biasStrip[bbase + row_in - col_in]);
          lrow[j][r] += p;
          Ps[row_in * 72 + col_in] = f2bf(p);
        }
      }
      // NO barrier: P rows are wave-private (same-wave LDS deps ordered).

      #pragma unroll
      for (int ks = 0; ks < 2; ++ks) {
        short8 a = *(const short8*)&Ps[(wv * 16 + lm) * 72 + ks * 32 + lq * 8];
        #pragma unroll
        for (int db = 0; db < 4; ++db) {
          short8 bfr = *(const short8*)&Vs[(db * 16 + lm) * 72 + ks * 32 + lq * 8];
          o[j][db] = __builtin_amdgcn_mfma_f32_16x16x32_bf16(a, bfr, o[j][db], 0, 0, 0);
        }
      }
    }
    __syncthreads();   // K/V reads done before next staging overwrites
  }

  // deferred l reductions across the 16-lane (lm) group; epilogue for both.
  #pragma unroll
  for (int j = 0; j < 2; ++j) {
    #pragma unroll
    for (int r = 0; r < 4; ++r) {
      #pragma unroll
      for (int off = 8; off; off >>= 1) lrow[j][r] += __shfl_xor(lrow[j][r], off);
    }
    #pragma unroll
    for (int r = 0; r < 4; ++r) {
      int qi = (qt0 + j) * 64 + wv * 16 + lq * 4 + r;
      float inv = 1.f / lrow[j][r];
      #pragma unroll
      for (int db = 0; db < 4; ++db) {
        int d = db * 16 + lm;
        ao[(size_t)(b * Nseq + qi) * Cdim + h * HD + d] = f2bf(o[j][db][r] * inv);
      }
    }
  }
}

// ------------- Stage 3: out = ao @ proj_w^T + proj_b (128x128 dbuf+T2) ------
__global__ __launch_bounds__(256, 2) void proj_gemm(
    const ushort* __restrict__ a, const ushort* __restrict__ w,
    const ushort* __restrict__ pb, float* __restrict__ out)
{
  __shared__ __align__(16) ushort As[2][128 * 64];   // 32 KB
  __shared__ __align__(16) ushort Ws[2][128 * 64];   // 32 KB (64 KB total)
  // XCD swizzle: 1536 blocks, 8 XCDs -> 192 contiguous per XCD.
  const int id = blockIdx.y * 6 + blockIdx.x;
  const int swz = (id & 7) * 192 + (id >> 3);
  const int bm = swz / 6;      // 0..255
  const int bn = swz % 6;      // 0..5
  const int t = threadIdx.x;
  const int wv = t >> 6, ln = t & 63, lq = ln >> 4, lm = ln & 15;
  const int wm = wv >> 1, wn = wv & 1;

  const int srow = ln >> 3;
  const int scol = (((ln & 7) ^ srow) << 3);
  const int cswz = (lm & 7) << 3;

  floatx4 acc[4][4];
  #pragma unroll
  for (int i = 0; i < 4; ++i)
    #pragma unroll
    for (int j = 0; j < 4; ++j) acc[i][j] = (floatx4)0.f;

  auto stage = [&](int buf, int kt) {
    #pragma unroll
    for (int p = 0; p < 4; ++p) {
      int c = wv * 4 + p;                // chunk 0..15, 8 rows each
      int row = c * 8 + srow;
      gload_lds16(&a[(size_t)(bm * 128 + row) * Cdim + kt * 64 + scol],
                  &As[buf][c * 512]);
      gload_lds16(&w[(size_t)(bn * 128 + row) * Cdim + kt * 64 + scol],
                  &Ws[buf][c * 512]);
    }
  };

  stage(0, 0);
  for (int kt = 0; kt < 12; ++kt) {
    const int cur = kt & 1;
    if (kt < 11) {
      stage(cur ^ 1, kt + 1);
      asm volatile("s_waitcnt vmcnt(8)" ::: "memory");
    } else {
      asm volatile("s_waitcnt vmcnt(0)" ::: "memory");
    }
    __builtin_amdgcn_s_barrier();
    #pragma unroll
    for (int ks = 0; ks < 2; ++ks) {
      short8 af[4], bfr[4];
      #pragma unroll
      for (int i = 0; i < 4; ++i)
        af[i] = *(const short8*)&As[cur][(wm * 64 + i * 16 + lm) * 64 +
                                         ((ks * 32 + lq * 8) ^ cswz)];
      #pragma unroll
      for (int j = 0; j < 4; ++j)
        bfr[j] = *(const short8*)&Ws[cur][(wn * 64 + j * 16 + lm) * 64 +
                                          ((ks * 32 + lq * 8) ^ cswz)];
      #pragma unroll
      for (int i = 0; i < 4; ++i)
        #pragma unroll
        for (int j = 0; j < 4; ++j)
          acc[i][j] = __builtin_amdgcn_mfma_f32_16x16x32_bf16(af[i], bfr[j], acc[i][j], 0, 0, 0);
    }
    asm volatile("s_waitcnt lgkmcnt(0)" ::: "memory");
    __builtin_amdgcn_s_barrier();
  }

  #pragma unroll
  for (int j = 0; j < 4; ++j) {
    int gn = bn * 128 + wn * 64 + j * 16 + lm;
    float bias = bf2f(pb[gn]);
    #pragma unroll
    for (int i = 0; i < 4; ++i) {
      #pragma unroll
      for (int r = 0; r < 4; ++r) {
        int gm = bm * 128 + wm * 64 + i * 16 + lq * 4 + r;
        out[(size_t)gm * Cdim + gn] = acc[i][j][r] + bias;
      }
    }
  }
}

extern "C" void kernel_launch(void* const* d_in, const int* in_sizes, int n_in,
                              void* d_out, int out_size, void* d_ws, size_t ws_size,
                              hipStream_t stream) {
  const float* x  = (const float*)d_in[0];   // [64,512,768] fp32
  const float* qw = (const float*)d_in[1];   // [2304,768]
  const float* pw = (const float*)d_in[2];   // [768,768]
  const float* pb = (const float*)d_in[3];   // [768]
  const float* bt = (const float*)d_in[4];   // [1023,12]
  float* out = (float*)d_out;                // [64,512,768] fp32

  constexpr int NX = Bsz * Nseq * Cdim;      // 24117248
  constexpr int NQW = 3 * Cdim * Cdim;       // 1769472
  constexpr int NPW = Cdim * Cdim;           // 589824
  constexpr int NBT = (2 * Nseq - 1) * NH;   // 12276

  ushort* qs  = (ushort*)d_ws;               // [B,H,N,hd] (q pre-scaled)
  ushort* ks  = qs + QS;
  ushort* vts = ks + QS;                     // [B,H,hd,N] (transposed)
  ushort* ao  = vts + QS;                    // attn out; shares space with xb
  ushort* xb  = ao;                          // xb dead before ao written
  ushort* qwb = ao + QS;
  ushort* pwb = qwb + NQW;
  ushort* pbb = pwb + NPW;
  ushort* btb = pbb + Cdim;                  // total ws ~206 MB

  cvt8<<<(NX  + 2047) / 2048, 256, 0, stream>>>(x,  xb,  NX);
  cvt8<<<(NQW + 2047) / 2048, 256, 0, stream>>>(qw, qwb, NQW);
  cvt8<<<(NPW + 2047) / 2048, 256, 0, stream>>>(pw, pwb, NPW);
  cvt8<<<1, 256, 0, stream>>>(pb, pbb, Cdim);
  cvt1s<<<(NBT + 255) / 256, 256, 0, stream>>>(bt, btb, NBT);

  qkv_gemm<<<dim3(18, 128), 512, 0, stream>>>(xb, qwb, qs, ks, vts);
  attn_kernel<<<dim3(Bsz * NH * (Nseq / 128)), 256, 0, stream>>>(qs, ks, vts, btb, ao);
  proj_gemm<<<dim3(6, 256), 256, 0, stream>>>(ao, pwb, pbb, out);
}

// Round 12
// 496.690 us; speedup vs baseline: 1.0565x; 1.0565x over previous
//
#include <hip/hip_runtime.h>
#include <hip/hip_bf16.h>

#define DI static __device__ __forceinline__

typedef __attribute__((ext_vector_type(8), may_alias)) short short8;
typedef __attribute__((ext_vector_type(4), may_alias)) short short4a;
typedef __attribute__((ext_vector_type(4), may_alias)) float floatx4a;
typedef __attribute__((ext_vector_type(4))) float floatx4;

constexpr int Bsz = 64, Nseq = 512, Cdim = 768, NH = 12, HD = 64;
constexpr int QS = Bsz * NH * Nseq * HD;  // 25165824
// q is pre-scaled by 0.125*log2(e); bias pre-scaled by log2(e); attn uses exp2.
constexpr float QK_PRESCALE = 0.18033688011112042f;  // 0.125 * log2(e)
constexpr float LOG2E = 1.4426950408889634f;

constexpr int NX  = Bsz * Nseq * Cdim;     // 24117248
constexpr int NQW = 3 * Cdim * Cdim;       // 1769472
constexpr int NPW = Cdim * Cdim;           // 589824
constexpr int NBT = (2 * Nseq - 1) * NH;   // 12276

// chunk counts (8 elems per chunk) for the merged converter
constexpr int XC  = NX / 8;                // 3014656
constexpr int QWC = NQW / 8;               // 221184
constexpr int PWC = NPW / 8;               // 73728
constexpr int PBC = Cdim / 8;              // 96
constexpr int BTC = (NBT + 7) / 8;         // 1535 (last chunk: 4 elems)
constexpr int ALLC = XC + QWC + PWC + PBC + BTC;  // 3311199

DI ushort f2bf(float f) {
  union { float f; unsigned u; } v; v.f = f;
  unsigned r = v.u + 0x7FFF + ((v.u >> 16) & 1);
  return (ushort)(r >> 16);
}
DI float bf2f(ushort u) {
  union { unsigned u; float f; } v; v.u = ((unsigned)u) << 16;
  return v.f;
}

// async global->LDS, 16B per lane. LDS dest is wave-uniform base + lane*16.
DI void gload_lds16(const ushort* g, ushort* l) {
  __builtin_amdgcn_global_load_lds(
      (const __attribute__((address_space(1))) unsigned int*)g,
      (__attribute__((address_space(3))) unsigned int*)l, 16, 0, 0);
}

// ------------- merged fp32 -> bf16 converter (was 5 launches, now 1) --------
// Segments: x | qkv_w | proj_w | proj_b | bias_table (bias gets *LOG2E).
// Launch-overhead fix: 4 tiny cvt kernels each cost ~5-10us of launch for
// ~2us of work; merged into one grid over chunk index.
__global__ void cvt_all(const float* __restrict__ x, const float* __restrict__ qw,
                        const float* __restrict__ pw, const float* __restrict__ pb,
                        const float* __restrict__ bt,
                        ushort* __restrict__ xb, ushort* __restrict__ qwb,
                        ushort* __restrict__ pwb, ushort* __restrict__ pbb,
                        ushort* __restrict__ btb) {
  int c = blockIdx.x * 256 + threadIdx.x;
  const float* s; ushort* d; float sc = 1.f; int cnt = 8;
  if (c < XC)                { s = x  + (size_t)c * 8; d = xb  + (size_t)c * 8; }
  else if ((c -= XC) < QWC)  { s = qw + (size_t)c * 8; d = qwb + (size_t)c * 8; }
  else if ((c -= QWC) < PWC) { s = pw + (size_t)c * 8; d = pwb + (size_t)c * 8; }
  else if ((c -= PWC) < PBC) { s = pb + (size_t)c * 8; d = pbb + (size_t)c * 8; }
  else if ((c -= PBC) < BTC) {
    s = bt + (size_t)c * 8; d = btb + (size_t)c * 8; sc = LOG2E;
    if (c * 8 + 8 > NBT) cnt = NBT - c * 8;          // 4-elem tail
  } else return;
  if (cnt == 8) {
    floatx4a a = *(const floatx4a*)s;
    floatx4a b = *(const floatx4a*)(s + 4);
    short8 r;
    r[0] = (short)f2bf(a[0] * sc); r[1] = (short)f2bf(a[1] * sc);
    r[2] = (short)f2bf(a[2] * sc); r[3] = (short)f2bf(a[3] * sc);
    r[4] = (short)f2bf(b[0] * sc); r[5] = (short)f2bf(b[1] * sc);
    r[6] = (short)f2bf(b[2] * sc); r[7] = (short)f2bf(b[3] * sc);
    *(short8*)d = r;
  } else {
    for (int j = 0; j < cnt; ++j) d[j] = f2bf(s[j] * sc);
  }
}

// ------------- Stage 1: qkv = x @ qkv_w^T -----------------------------------
// REVERTED to the proven R9 256x256 2-buffer + counted vmcnt(8) + T2 swizzle
// (156us, FETCH 100MB, conflicts 0). R11's 256x128 3-buffer regressed:
// FETCH 100->161MB (2x A re-reads from narrower BN), MfmaUtil 31->26.
__global__ __launch_bounds__(512, 2) void qkv_gemm(
    const ushort* __restrict__ x, const ushort* __restrict__ w,
    ushort* __restrict__ qo, ushort* __restrict__ ko, ushort* __restrict__ vo)
{
  __shared__ __align__(16) ushort As[2][256 * 64];   // 64 KB
  __shared__ __align__(16) ushort Ws[2][256 * 64];   // 64 KB  (128 KB total)
  // XCD swizzle: 1152 blocks, 8 XCDs -> 144 contiguous per XCD.
  const int id = blockIdx.y * 9 + blockIdx.x;
  const int swz = (id & 7) * 144 + (id >> 3);
  const int bm = swz / 9;      // 0..127  (32768/256)
  const int bn = swz % 9;      // 0..8    (2304/256)
  const int t = threadIdx.x;
  const int wv = t >> 6, ln = t & 63, lq = ln >> 4, lm = ln & 15;
  const int wm = wv >> 2, wn = wv & 3;   // wave tile: rows wm*128+, cols wn*64+

  const int srow = ln >> 3;              // 0..7 within an 8-row chunk (= row&7)
  const int scol = (((ln & 7) ^ srow) << 3);   // T2 pre-swizzled source col
  const int cswz = (lm & 7) << 3;              // read-side XOR

  floatx4 acc[8][4];
  #pragma unroll
  for (int i = 0; i < 8; ++i)
    #pragma unroll
    for (int j = 0; j < 4; ++j) acc[i][j] = (floatx4)0.f;

  auto stage = [&](int buf, int kt) {
    #pragma unroll
    for (int p = 0; p < 4; ++p) {
      int c = wv * 4 + p;                // chunk 0..31, 8 rows each
      int row = c * 8 + srow;
      gload_lds16(&x[(size_t)(bm * 256 + row) * Cdim + kt * 64 + scol],
                  &As[buf][c * 512]);
      gload_lds16(&w[(size_t)(bn * 256 + row) * Cdim + kt * 64 + scol],
                  &Ws[buf][c * 512]);
    }
  };

  stage(0, 0);
  for (int kt = 0; kt < 12; ++kt) {
    const int cur = kt & 1;
    if (kt < 11) {
      stage(cur ^ 1, kt + 1);
      asm volatile("s_waitcnt vmcnt(8)" ::: "memory");  // cur's 8 loads done
    } else {
      asm volatile("s_waitcnt vmcnt(0)" ::: "memory");
    }
    __builtin_amdgcn_s_barrier();
    #pragma unroll
    for (int ks = 0; ks < 2; ++ks) {
      short8 af[8], bfr[4];
      #pragma unroll
      for (int i = 0; i < 8; ++i)
        af[i] = *(const short8*)&As[cur][(wm * 128 + i * 16 + lm) * 64 +
                                         ((ks * 32 + lq * 8) ^ cswz)];
      #pragma unroll
      for (int j = 0; j < 4; ++j)
        bfr[j] = *(const short8*)&Ws[cur][(wn * 64 + j * 16 + lm) * 64 +
                                          ((ks * 32 + lq * 8) ^ cswz)];
      #pragma unroll
      for (int i = 0; i < 8; ++i)
        #pragma unroll
        for (int j = 0; j < 4; ++j)
          acc[i][j] = __builtin_amdgcn_mfma_f32_16x16x32_bf16(af[i], bfr[j], acc[i][j], 0, 0, 0);
    }
    asm volatile("s_waitcnt lgkmcnt(0)" ::: "memory");  // our reads done
    __builtin_amdgcn_s_barrier();                       // before buf overwrite
  }

  // Epilogue. 64-col wave block lies entirely in one (which, head).
  const int cbase = bn * 256 + wn * 64;
  const int which = cbase / Cdim;            // 0=q 1=k 2=v
  const int h = (cbase % Cdim) >> 6;
  const float osc = (which == 0) ? QK_PRESCALE : 1.f;
  #pragma unroll
  for (int i = 0; i < 8; ++i) {
    int gm0 = bm * 256 + wm * 128 + i * 16 + lq * 4;
    int b = gm0 >> 9, ns0 = gm0 & 511;       // 4-run stays within one (b,ns-run)
    #pragma unroll
    for (int j = 0; j < 4; ++j) {
      int d = j * 16 + lm;
      if (which == 2) {
        short4a v4;
        #pragma unroll
        for (int r = 0; r < 4; ++r) v4[r] = (short)f2bf(acc[i][j][r]);
        *(short4a*)&vo[(size_t)((b * NH + h) * HD + d) * Nseq + ns0] = v4;
      } else {
        ushort* outp = which == 0 ? qo : ko;
        #pragma unroll
        for (int r = 0; r < 4; ++r)
          outp[(size_t)((b * NH + h) * Nseq + ns0 + r) * HD + d] = f2bf(acc[i][j][r] * osc);
      }
    }
  }
}

// ------------- Stage 2: flash attention, 2 q-tiles per block (unchanged) ----
__global__ __launch_bounds__(256) void attn_kernel(
    const ushort* __restrict__ q, const ushort* __restrict__ k,
    const ushort* __restrict__ vt, const ushort* __restrict__ bt,
    ushort* __restrict__ ao)
{
  __shared__ __align__(16) ushort Ks[64 * 72];
  __shared__ __align__(16) ushort Vs[64 * 72];   // Vt tile: [d][n]
  __shared__ __align__(16) ushort Ps[64 * 72];
  __shared__ float biasStrip[640];
  const int blk = blockIdx.x;
  const int xcd = blk & 7;
  const int slot = blk >> 3;               // 0..383
  const int qp = slot & 3;                 // q-tile PAIR {2qp, 2qp+1}
  const int bh = xcd * 96 + (slot >> 2);   // head pinned to one XCD
  const int h = bh % NH, b = bh / NH;
  const int t = threadIdx.x;
  const int wv = t >> 6, ln = t & 63, lq = ln >> 4, lm = ln & 15;
  const size_t base = (size_t)bh * (Nseq * HD);
  const int qt0 = qp * 2;

  // Q fragments for both q-tiles straight from global (per-lane 16B).
  short8 qa[2][2];
  #pragma unroll
  for (int j = 0; j < 2; ++j)
    #pragma unroll
    for (int ks = 0; ks < 2; ++ks)
      qa[j][ks] = *(const short8*)&q[base +
          (size_t)((qt0 + j) * 64 + wv * 16 + lm) * HD + ks * 32 + lq * 8];

  // bias strip: rel = qt0*64 + j, j in [0,639]; max index (6*64+638)=1022 OK.
  for (int j = t; j < 640; j += 256)
    biasStrip[j] = bf2f(bt[(qt0 * 64 + j) * NH + h]);

  floatx4 o[2][4];
  float lrow[2][4];
  #pragma unroll
  for (int j = 0; j < 2; ++j)
    #pragma unroll
    for (int i = 0; i < 4; ++i) { o[j][i] = (floatx4)0.f; lrow[j][i] = 0.f; }

  for (int kt = 0; kt < Nseq / 64; ++kt) {
    #pragma unroll
    for (int i = 0; i < 2; ++i) {
      int id = t + 256 * i;
      int r = id >> 3, c = (id & 7) << 3;
      *(short8*)&Ks[r * 72 + c] =
          *(const short8*)&k[base + (size_t)(kt * 64 + r) * HD + c];
      *(short8*)&Vs[r * 72 + c] =                      // row r = d, col c = n
          *(const short8*)&vt[base + (size_t)r * Nseq + kt * 64 + c];
    }
    __syncthreads();   // staging visible (also covers biasStrip on kt==0)

    #pragma unroll
    for (int j = 0; j < 2; ++j) {        // q-tile within the pair
      floatx4 s[4];
      #pragma unroll
      for (int cb = 0; cb < 4; ++cb) s[cb] = (floatx4)0.f;
      #pragma unroll
      for (int ks = 0; ks < 2; ++ks) {
        #pragma unroll
        for (int cb = 0; cb < 4; ++cb) {
          short8 bfr = *(const short8*)&Ks[(cb * 16 + lm) * 72 + ks * 32 + lq * 8];
          s[cb] = __builtin_amdgcn_mfma_f32_16x16x32_bf16(qa[j][ks], bfr, s[cb], 0, 0, 0);
        }
      }

      // p = exp2(s + bias); bias index = (j-kt)*64 + 511 + (row-col)
      const int bbase = j * 64 - kt * 64 + 511;
      #pragma unroll
      for (int r = 0; r < 4; ++r) {
        int row_in = wv * 16 + lq * 4 + r;
        #pragma unroll
        for (int cb = 0; cb < 4; ++cb) {
          int col_in = cb * 16 + lm;
          float p = __builtin_amdgcn_exp2f(s[cb][r] +
                                           biasStrip[bbase + row_in - col_in]);
          lrow[j][r] += p;
          Ps[row_in * 72 + col_in] = f2bf(p);
        }
      }
      // NO barrier: P rows are wave-private (same-wave LDS deps ordered).

      #pragma unroll
      for (int ks = 0; ks < 2; ++ks) {
        short8 a = *(const short8*)&Ps[(wv * 16 + lm) * 72 + ks * 32 + lq * 8];
        #pragma unroll
        for (int db = 0; db < 4; ++db) {
          short8 bfr = *(const short8*)&Vs[(db * 16 + lm) * 72 + ks * 32 + lq * 8];
          o[j][db] = __builtin_amdgcn_mfma_f32_16x16x32_bf16(a, bfr, o[j][db], 0, 0, 0);
        }
      }
    }
    __syncthreads();   // K/V reads done before next staging overwrites
  }

  // deferred l reductions across the 16-lane (lm) group; epilogue for both.
  #pragma unroll
  for (int j = 0; j < 2; ++j) {
    #pragma unroll
    for (int r = 0; r < 4; ++r) {
      #pragma unroll
      for (int off = 8; off; off >>= 1) lrow[j][r] += __shfl_xor(lrow[j][r], off);
    }
    #pragma unroll
    for (int r = 0; r < 4; ++r) {
      int qi = (qt0 + j) * 64 + wv * 16 + lq * 4 + r;
      float inv = 1.f / lrow[j][r];
      #pragma unroll
      for (int db = 0; db < 4; ++db) {
        int d = db * 16 + lm;
        ao[(size_t)(b * Nseq + qi) * Cdim + h * HD + d] = f2bf(o[j][db][r] * inv);
      }
    }
  }
}

// ------------- Stage 3: out = ao @ proj_w^T + proj_b (128x128 dbuf+T2) ------
__global__ __launch_bounds__(256, 2) void proj_gemm(
    const ushort* __restrict__ a, const ushort* __restrict__ w,
    const ushort* __restrict__ pb, float* __restrict__ out)
{
  __shared__ __align__(16) ushort As[2][128 * 64];   // 32 KB
  __shared__ __align__(16) ushort Ws[2][128 * 64];   // 32 KB (64 KB total)
  // XCD swizzle: 1536 blocks, 8 XCDs -> 192 contiguous per XCD.
  const int id = blockIdx.y * 6 + blockIdx.x;
  const int swz = (id & 7) * 192 + (id >> 3);
  const int bm = swz / 6;      // 0..255
  const int bn = swz % 6;      // 0..5
  const int t = threadIdx.x;
  const int wv = t >> 6, ln = t & 63, lq = ln >> 4, lm = ln & 15;
  const int wm = wv >> 1, wn = wv & 1;

  const int srow = ln >> 3;
  const int scol = (((ln & 7) ^ srow) << 3);
  const int cswz = (lm & 7) << 3;

  floatx4 acc[4][4];
  #pragma unroll
  for (int i = 0; i < 4; ++i)
    #pragma unroll
    for (int j = 0; j < 4; ++j) acc[i][j] = (floatx4)0.f;

  auto stage = [&](int buf, int kt) {
    #pragma unroll
    for (int p = 0; p < 4; ++p) {
      int c = wv * 4 + p;                // chunk 0..15, 8 rows each
      int row = c * 8 + srow;
      gload_lds16(&a[(size_t)(bm * 128 + row) * Cdim + kt * 64 + scol],
                  &As[buf][c * 512]);
      gload_lds16(&w[(size_t)(bn * 128 + row) * Cdim + kt * 64 + scol],
                  &Ws[buf][c * 512]);
    }
  };

  stage(0, 0);
  for (int kt = 0; kt < 12; ++kt) {
    const int cur = kt & 1;
    if (kt < 11) {
      stage(cur ^ 1, kt + 1);
      asm volatile("s_waitcnt vmcnt(8)" ::: "memory");
    } else {
      asm volatile("s_waitcnt vmcnt(0)" ::: "memory");
    }
    __builtin_amdgcn_s_barrier();
    #pragma unroll
    for (int ks = 0; ks < 2; ++ks) {
      short8 af[4], bfr[4];
      #pragma unroll
      for (int i = 0; i < 4; ++i)
        af[i] = *(const short8*)&As[cur][(wm * 64 + i * 16 + lm) * 64 +
                                         ((ks * 32 + lq * 8) ^ cswz)];
      #pragma unroll
      for (int j = 0; j < 4; ++j)
        bfr[j] = *(const short8*)&Ws[cur][(wn * 64 + j * 16 + lm) * 64 +
                                          ((ks * 32 + lq * 8) ^ cswz)];
      #pragma unroll
      for (int i = 0; i < 4; ++i)
        #pragma unroll
        for (int j = 0; j < 4; ++j)
          acc[i][j] = __builtin_amdgcn_mfma_f32_16x16x32_bf16(af[i], bfr[j], acc[i][j], 0, 0, 0);
    }
    asm volatile("s_waitcnt lgkmcnt(0)" ::: "memory");
    __builtin_amdgcn_s_barrier();
  }

  #pragma unroll
  for (int j = 0; j < 4; ++j) {
    int gn = bn * 128 + wn * 64 + j * 16 + lm;
    float bias = bf2f(pb[gn]);
    #pragma unroll
    for (int i = 0; i < 4; ++i) {
      #pragma unroll
      for (int r = 0; r < 4; ++r) {
        int gm = bm * 128 + wm * 64 + i * 16 + lq * 4 + r;
        out[(size_t)gm * Cdim + gn] = acc[i][j][r] + bias;
      }
    }
  }
}

extern "C" void kernel_launch(void* const* d_in, const int* in_sizes, int n_in,
                              void* d_out, int out_size, void* d_ws, size_t ws_size,
                              hipStream_t stream) {
  const float* x  = (const float*)d_in[0];   // [64,512,768] fp32
  const float* qw = (const float*)d_in[1];   // [2304,768]
  const float* pw = (const float*)d_in[2];   // [768,768]
  const float* pb = (const float*)d_in[3];   // [768]
  const float* bt = (const float*)d_in[4];   // [1023,12]
  float* out = (float*)d_out;                // [64,512,768] fp32

  ushort* qs  = (ushort*)d_ws;               // [B,H,N,hd] (q pre-scaled)
  ushort* ks  = qs + QS;
  ushort* vts = ks + QS;                     // [B,H,hd,N] (transposed)
  ushort* ao  = vts + QS;                    // attn out; shares space with xb
  ushort* xb  = ao;                          // xb dead before ao written
  ushort* qwb = ao + QS;
  ushort* pwb = qwb + NQW;
  ushort* pbb = pwb + NPW;
  ushort* btb = pbb + Cdim;                  // total ws ~206 MB

  cvt_all<<<(ALLC + 255) / 256, 256, 0, stream>>>(x, qw, pw, pb, bt,
                                                  xb, qwb, pwb, pbb, btb);

  qkv_gemm<<<dim3(9, 128), 512, 0, stream>>>(xb, qwb, qs, ks, vts);
  attn_kernel<<<dim3(Bsz * NH * (Nseq / 128)), 256, 0, stream>>>(qs, ks, vts, btb, ao);
  proj_gemm<<<dim3(6, 256), 256, 0, stream>>>(ao, pwb, pbb, out);
}